// Round 1
// baseline (362.409 us; speedup 1.0000x reference)
//
#include <hip/hip_runtime.h>

// GraphSAGE 3-layer, N=10000 nodes, E=640000 edges, D = 128 -> 128 -> 64.
// Key rewrite: aggregate AFTER the matmul (linearity of mean-aggregation),
// and build CSR by edge_dst once per call so aggregation has no fp32 atomics.

#define NN 10000
#define NE 640000

// ---------------- CSR build ----------------

__global__ void zero_ints(int* __restrict__ p, int n) {
    int i = blockIdx.x * blockDim.x + threadIdx.x;
    if (i < n) p[i] = 0;
}

__global__ void count_k(const int* __restrict__ dst, int* __restrict__ counts, int e) {
    int i = blockIdx.x * blockDim.x + threadIdx.x;
    if (i < e) atomicAdd(&counts[dst[i]], 1);
}

// single-block exclusive scan over counts[0..n) -> offs[0..n]
__global__ void scan_k(const int* __restrict__ counts, int* __restrict__ offs, int n) {
    __shared__ int sums[256];
    int tid = threadIdx.x;
    int chunk = (n + 255) / 256;
    int start = tid * chunk; if (start > n) start = n;
    int end = start + chunk; if (end > n) end = n;
    int s = 0;
    for (int i = start; i < end; ++i) s += counts[i];
    sums[tid] = s;
    __syncthreads();
    for (int off = 1; off < 256; off <<= 1) {
        int t = (tid >= off) ? sums[tid - off] : 0;
        __syncthreads();
        sums[tid] += t;
        __syncthreads();
    }
    int prefix = sums[tid] - s;   // exclusive prefix of this thread's chunk
    for (int i = start; i < end; ++i) { offs[i] = prefix; prefix += counts[i]; }
    if (tid == 255) offs[n] = sums[255];
}

__global__ void fill_k(const int* __restrict__ src, const int* __restrict__ dst,
                       const int* __restrict__ offs, int* __restrict__ fill,
                       int* __restrict__ ssrc, int e) {
    int i = blockIdx.x * blockDim.x + threadIdx.x;
    if (i < e) {
        int d = dst[i];
        int pos = offs[d] + atomicAdd(&fill[d], 1);
        ssrc[pos] = src[i];
    }
}

// ---------------- dense dual matmul: hs = h@Ws + b, hn = h@Wn ----------------
// K fixed at 128. M = 128 or 64. Tile: ROWS=32 rows per block, 256 threads.

template <int M>
__global__ void dense_dual(const float* __restrict__ h,
                           const float* __restrict__ Ws,
                           const float* __restrict__ Wn,
                           const float* __restrict__ b,
                           float* __restrict__ hs, float* __restrict__ hn, int n) {
    constexpr int K = 128;
    constexpr int ROWS = 32;
    constexpr int R = ROWS * M / 256;      // rows per thread (16 for M=128, 8 for M=64)
    __shared__ float sh[ROWS * K];

    int row0 = blockIdx.x * ROWS;
    int tid = threadIdx.x;

    // stage the 32xK row tile (coalesced float4)
    constexpr int NVEC = ROWS * K / 4;     // 1024
    const float4* hv = (const float4*)(h + (size_t)row0 * K);
    float4* shv = (float4*)sh;
    int maxvec = (n - row0) * (K / 4);     // float4s actually available
    for (int i = tid; i < NVEC; i += 256) {
        float4 v = (i < maxvec) ? hv[i] : make_float4(0.f, 0.f, 0.f, 0.f);
        shv[i] = v;
    }
    __syncthreads();

    int col = tid % M;
    int rg = tid / M;                      // row group
    float accs[R], accn[R];
#pragma unroll
    for (int r = 0; r < R; ++r) { accs[r] = 0.f; accn[r] = 0.f; }

    for (int k = 0; k < K; k += 4) {
        float ws0 = Ws[(k + 0) * M + col];
        float ws1 = Ws[(k + 1) * M + col];
        float ws2 = Ws[(k + 2) * M + col];
        float ws3 = Ws[(k + 3) * M + col];
        float wn0 = Wn[(k + 0) * M + col];
        float wn1 = Wn[(k + 1) * M + col];
        float wn2 = Wn[(k + 2) * M + col];
        float wn3 = Wn[(k + 3) * M + col];
#pragma unroll
        for (int r = 0; r < R; ++r) {
            float4 a = *(const float4*)&sh[(rg * R + r) * K + k];   // wave-broadcast
            accs[r] += a.x * ws0 + a.y * ws1 + a.z * ws2 + a.w * ws3;
            accn[r] += a.x * wn0 + a.y * wn1 + a.z * wn2 + a.w * wn3;
        }
    }

    float bias = b[col];
#pragma unroll
    for (int r = 0; r < R; ++r) {
        int row = row0 + rg * R + r;
        if (row < n) {
            hs[(size_t)row * M + col] = accs[r] + bias;
            hn[(size_t)row * M + col] = accn[r];
        }
    }
}

// ---------------- fused aggregate + combine (+ReLU) ----------------
// out[node] = hs[node] + (sum_{e in CSR(node)} hn[src_e]) / max(deg,1); optional ReLU.

template <int M, bool RELU>
__global__ void agg_combine(const float* __restrict__ hs, const float* __restrict__ hn,
                            const int* __restrict__ offs, const int* __restrict__ ssrc,
                            float* __restrict__ out, int n) {
    constexpr int NPB = 256 / M;           // nodes per block
    int node = blockIdx.x * NPB + threadIdx.x / M;
    int f = threadIdx.x % M;
    if (node >= n) return;
    int beg = offs[node];
    int end = offs[node + 1];
    float acc = 0.f;
    int e = beg;
    for (; e + 4 <= end; e += 4) {
        int s0 = ssrc[e + 0];
        int s1 = ssrc[e + 1];
        int s2 = ssrc[e + 2];
        int s3 = ssrc[e + 3];
        float v0 = hn[(size_t)s0 * M + f];
        float v1 = hn[(size_t)s1 * M + f];
        float v2 = hn[(size_t)s2 * M + f];
        float v3 = hn[(size_t)s3 * M + f];
        acc += v0 + v1 + v2 + v3;
    }
    for (; e < end; ++e) acc += hn[(size_t)ssrc[e] * M + f];
    int deg = end - beg;
    float scale = 1.0f / (float)(deg > 0 ? deg : 1);
    float v = hs[(size_t)node * M + f] + acc * scale;
    if (RELU) v = fmaxf(v, 0.f);
    out[(size_t)node * M + f] = v;
}

// ---------------- launch ----------------

extern "C" void kernel_launch(void* const* d_in, const int* in_sizes, int n_in,
                              void* d_out, int out_size, void* d_ws, size_t ws_size,
                              hipStream_t stream) {
    const float* x   = (const float*)d_in[0];
    const float* Ws0 = (const float*)d_in[1];
    const float* Wn0 = (const float*)d_in[2];
    const float* b0  = (const float*)d_in[3];
    const float* Ws1 = (const float*)d_in[4];
    const float* Wn1 = (const float*)d_in[5];
    const float* b1  = (const float*)d_in[6];
    const float* Ws2 = (const float*)d_in[7];
    const float* Wn2 = (const float*)d_in[8];
    const float* b2  = (const float*)d_in[9];
    const int* esrc  = (const int*)d_in[10];
    const int* edst  = (const int*)d_in[11];
    float* out = (float*)d_out;

    // workspace layout (all fp32/int32, 4-byte elems; float4 users are 16B-aligned)
    float* hA = (float*)d_ws;              // NN*128
    float* hB = hA + (size_t)NN * 128;     // NN*128
    float* hs = hB + (size_t)NN * 128;     // NN*128
    float* hn = hs + (size_t)NN * 128;     // NN*128
    int* counts = (int*)(hn + (size_t)NN * 128);  // NN
    int* offs   = counts + NN;             // NN+1
    int* fill   = offs + NN + 1;           // NN
    int* ssrc   = fill + NN;               // NE

    const int EB = (NE + 255) / 256;       // 2500

    // CSR build (edge_dst is an input, rebuilt every call; deterministic)
    zero_ints<<<(2 * NN + 255) / 256, 256, 0, stream>>>(counts, 2 * NN);  // counts then (via layout) not fill!
    zero_ints<<<(NN + 255) / 256, 256, 0, stream>>>(fill, NN);
    count_k<<<EB, 256, 0, stream>>>(edst, counts, NE);
    scan_k<<<1, 256, 0, stream>>>(counts, offs, NN);
    fill_k<<<EB, 256, 0, stream>>>(esrc, edst, offs, fill, ssrc, NE);

    const int DB = (NN + 31) / 32;         // 313 dense blocks

    // layer 0: 128 -> 128, ReLU
    dense_dual<128><<<DB, 256, 0, stream>>>(x, Ws0, Wn0, b0, hs, hn, NN);
    agg_combine<128, true><<<(NN + 1) / 2, 256, 0, stream>>>(hs, hn, offs, ssrc, hA, NN);

    // layer 1: 128 -> 128, ReLU
    dense_dual<128><<<DB, 256, 0, stream>>>(hA, Ws1, Wn1, b1, hs, hn, NN);
    agg_combine<128, true><<<(NN + 1) / 2, 256, 0, stream>>>(hs, hn, offs, ssrc, hB, NN);

    // layer 2: 128 -> 64, no ReLU, straight to d_out
    dense_dual<64><<<DB, 256, 0, stream>>>(hB, Ws2, Wn2, b2, hs, hn, NN);
    agg_combine<64, false><<<(NN + 3) / 4, 256, 0, stream>>>(hs, hn, offs, ssrc, out, NN);
}

// Round 2
// 280.802 us; speedup vs baseline: 1.2906x; 1.2906x over previous
//
#include <hip/hip_runtime.h>
#include <hip/hip_bf16.h>

// GraphSAGE 3-layer, N=10000, E=640000, D=128->128->64.
// - Aggregate AFTER the neighbor matmul (linearity of mean aggregation).
// - CSR built via two-level LDS counting sort: no 640K-global-atomic kernels,
//   no 4B-granule scattered writes (R1 profile: fill_k wrote 36MB for a 2.56MB
//   array at 870GB/s partial-line rate).
// - Neighbor-matmul output stored bf16 (2.56MB table -> fits one XCD L2,
//   halves the irregular gather traffic). Self path + accumulation stay fp32.
// - Layer-0 dense matmul fused into the fine-sort dispatch (independent work;
//   single stream can't overlap dispatches, one fat kernel can).

#define NN 10000
#define NE 640000
#define NBINS 313      // coarse bin = dst >> 5 (32 nodes per bin)
#define NBLKA 250      // histogram/scatter blocks
#define CHUNK 2560     // edges per block (250*2560 == 640000)
#define SORT_CAP 4096  // LDS staging ints for fine sort (expected ~2048/bin)

// ---------------- pass A: per-block coarse histograms (LDS atomics only) ----

__global__ void hist_k(const int* __restrict__ dst, int* __restrict__ blockhist) {
    __shared__ int h[NBINS];
    int tid = threadIdx.x;
    for (int i = tid; i < NBINS; i += 256) h[i] = 0;
    __syncthreads();
    int base = blockIdx.x * CHUNK;
    for (int i = tid; i < CHUNK; i += 256)
        atomicAdd(&h[dst[base + i] >> 5], 1);
    __syncthreads();
    for (int i = tid; i < NBINS; i += 256)
        blockhist[blockIdx.x * NBINS + i] = h[i];
}

// ---------------- pass S: scan (block,bin) matrix + bin starts --------------

__global__ void scan2_k(const int* __restrict__ blockhist,
                        int* __restrict__ offmat, int* __restrict__ binstart) {
    __shared__ int tot[NBINS];
    int tid = threadIdx.x;
    for (int bin = tid; bin < NBINS; bin += 256) {
        int run = 0;
        for (int blk = 0; blk < NBLKA; ++blk) {
            offmat[bin * NBLKA + blk] = run;
            run += blockhist[blk * NBINS + bin];
        }
        tot[bin] = run;
    }
    __syncthreads();
    if (tid == 0) {
        int run = 0;
        for (int i = 0; i < NBINS; ++i) { binstart[i] = run; run += tot[i]; }
        binstart[NBINS] = run;   // == NE
    }
}

// ---------------- pass B: scatter packed edges into bin-grouped tmp ---------

__global__ void scatter_k(const int* __restrict__ src, const int* __restrict__ dst,
                          const int* __restrict__ offmat, const int* __restrict__ binstart,
                          unsigned* __restrict__ tmp) {
    __shared__ int cur[NBINS];
    int tid = threadIdx.x, blk = blockIdx.x;
    for (int i = tid; i < NBINS; i += 256)
        cur[i] = binstart[i] + offmat[i * NBLKA + blk];
    __syncthreads();
    int base = blk * CHUNK;
    for (int i = tid; i < CHUNK; i += 256) {
        int d = dst[base + i], s = src[base + i];
        int pos = atomicAdd(&cur[d >> 5], 1);
        tmp[pos] = ((unsigned)s << 5) | (unsigned)(d & 31);   // src:14b | dstloc:5b
    }
}

// ---------------- pass C: per-bin fine sort -> offs[] + ssrc[] --------------

__device__ void bin_sort_body(const unsigned* __restrict__ tmp,
                              const int* __restrict__ binstart,
                              int* __restrict__ offs, int* __restrict__ ssrc,
                              int b, int* stage) {
    __shared__ int cnt32[32];
    __shared__ int cur32[32];
    int tid = threadIdx.x;
    int beg = binstart[b], end = binstart[b + 1], cnt = end - beg;
    if (tid < 32) cnt32[tid] = 0;
    __syncthreads();
    for (int i = tid; i < cnt; i += 256)
        atomicAdd(&cnt32[tmp[beg + i] & 31], 1);
    __syncthreads();
    if (tid == 0) {
        int run = 0;
        for (int i = 0; i < 32; ++i) {
            int node = b * 32 + i;
            if (node < NN) offs[node] = beg + run;
            cur32[i] = run;
            run += cnt32[i];
        }
        if (b == NBINS - 1) offs[NN] = end;
    }
    __syncthreads();
    if (cnt <= SORT_CAP) {
        for (int i = tid; i < cnt; i += 256) {
            unsigned p = tmp[beg + i];
            int pos = atomicAdd(&cur32[p & 31], 1);
            stage[pos] = (int)(p >> 5);
        }
        __syncthreads();
        for (int i = tid; i < cnt; i += 256)   // coalesced stream-out
            ssrc[beg + i] = stage[i];
    } else {                                    // safety fallback (never expected)
        for (int i = tid; i < cnt; i += 256) {
            unsigned p = tmp[beg + i];
            int pos = atomicAdd(&cur32[p & 31], 1);
            ssrc[beg + pos] = (int)(p >> 5);
        }
    }
}

// ---------------- dense dual matmul: hs = h@Ws + b (f32), hnb = h@Wn (bf16) -

template <int M>
__device__ void dense_body(const float* __restrict__ h,
                           const float* __restrict__ Ws,
                           const float* __restrict__ Wn,
                           const float* __restrict__ bias,
                           float* __restrict__ hs, __hip_bfloat16* __restrict__ hnb,
                           int blk, float* sh) {
    constexpr int K = 128;
    constexpr int ROWS = 32;
    constexpr int R = ROWS * M / 256;      // rows per thread
    int row0 = blk * ROWS;
    int tid = threadIdx.x;

    constexpr int NVEC = ROWS * K / 4;     // 1024 float4s
    const float4* hv = (const float4*)(h + (size_t)row0 * K);
    float4* shv = (float4*)sh;
    int maxvec = (NN - row0) * (K / 4);
    for (int i = tid; i < NVEC; i += 256)
        shv[i] = (i < maxvec) ? hv[i] : make_float4(0.f, 0.f, 0.f, 0.f);
    __syncthreads();

    int col = tid % M;
    int rg = tid / M;
    float accs[R], accn[R];
#pragma unroll
    for (int r = 0; r < R; ++r) { accs[r] = 0.f; accn[r] = 0.f; }

    for (int k = 0; k < K; k += 4) {
        float ws0 = Ws[(k + 0) * M + col];
        float ws1 = Ws[(k + 1) * M + col];
        float ws2 = Ws[(k + 2) * M + col];
        float ws3 = Ws[(k + 3) * M + col];
        float wn0 = Wn[(k + 0) * M + col];
        float wn1 = Wn[(k + 1) * M + col];
        float wn2 = Wn[(k + 2) * M + col];
        float wn3 = Wn[(k + 3) * M + col];
#pragma unroll
        for (int r = 0; r < R; ++r) {
            float4 a = *(const float4*)&sh[(rg * R + r) * K + k];
            accs[r] += a.x * ws0 + a.y * ws1 + a.z * ws2 + a.w * ws3;
            accn[r] += a.x * wn0 + a.y * wn1 + a.z * wn2 + a.w * wn3;
        }
    }

    float bv = bias[col];
#pragma unroll
    for (int r = 0; r < R; ++r) {
        int row = row0 + rg * R + r;
        if (row < NN) {
            hs[(size_t)row * M + col] = accs[r] + bv;
            hnb[(size_t)row * M + col] = __float2bfloat16(accn[r]);
        }
    }
}

template <int M>
__global__ void dense_dual(const float* __restrict__ h, const float* __restrict__ Ws,
                           const float* __restrict__ Wn, const float* __restrict__ b,
                           float* __restrict__ hs, __hip_bfloat16* __restrict__ hnb) {
    __shared__ float4 sh4[32 * 128 / 4];
    dense_body<M>(h, Ws, Wn, b, hs, hnb, blockIdx.x, (float*)sh4);
}

// fused: blocks [0,NBINS) fine-sort, blocks [NBINS, NBINS+313) dense layer 0
__global__ void sortC_dense0(const unsigned* __restrict__ tmp, const int* __restrict__ binstart,
                             int* __restrict__ offs, int* __restrict__ ssrc,
                             const float* __restrict__ x, const float* __restrict__ Ws0,
                             const float* __restrict__ Wn0, const float* __restrict__ b0,
                             float* __restrict__ hs, __hip_bfloat16* __restrict__ hnb) {
    __shared__ float4 shb[SORT_CAP / 4];   // 16KB, shared by both roles
    if ((int)blockIdx.x < NBINS)
        bin_sort_body(tmp, binstart, offs, ssrc, blockIdx.x, (int*)shb);
    else
        dense_body<128>(x, Ws0, Wn0, b0, hs, hnb, blockIdx.x - NBINS, (float*)shb);
}

// ---------------- fused aggregate + combine (+ReLU), bf16 gathers -----------
// out[node] = hs[node] + (sum over CSR(node) of hnb[src]) / max(deg,1)

template <int M, bool RELU>
__global__ void agg_combine(const float* __restrict__ hs, const unsigned* __restrict__ hnu,
                            const int* __restrict__ offs, const int* __restrict__ ssrc,
                            float* __restrict__ out, int n) {
    constexpr int TPN = M / 2;             // threads per node (feature pairs)
    constexpr int NPB = 256 / TPN;         // nodes per block
    int node = blockIdx.x * NPB + threadIdx.x / TPN;
    int t = threadIdx.x % TPN;
    if (node >= n) return;
    int beg = offs[node], end = offs[node + 1];
    float a0 = 0.f, a1 = 0.f;
    int e = beg;
    for (; e + 4 <= end; e += 4) {
        int s0 = ssrc[e], s1 = ssrc[e + 1], s2 = ssrc[e + 2], s3 = ssrc[e + 3];
        unsigned v0 = hnu[(size_t)s0 * TPN + t];
        unsigned v1 = hnu[(size_t)s1 * TPN + t];
        unsigned v2 = hnu[(size_t)s2 * TPN + t];
        unsigned v3 = hnu[(size_t)s3 * TPN + t];
        a0 += __uint_as_float(v0 << 16) + __uint_as_float(v1 << 16)
            + __uint_as_float(v2 << 16) + __uint_as_float(v3 << 16);
        a1 += __uint_as_float(v0 & 0xFFFF0000u) + __uint_as_float(v1 & 0xFFFF0000u)
            + __uint_as_float(v2 & 0xFFFF0000u) + __uint_as_float(v3 & 0xFFFF0000u);
    }
    for (; e < end; ++e) {
        unsigned v = hnu[(size_t)ssrc[e] * TPN + t];
        a0 += __uint_as_float(v << 16);
        a1 += __uint_as_float(v & 0xFFFF0000u);
    }
    int deg = end - beg;
    float sc = 1.0f / (float)(deg > 0 ? deg : 1);
    float2 h2 = ((const float2*)hs)[(size_t)node * TPN + t];
    float r0 = h2.x + a0 * sc;
    float r1 = h2.y + a1 * sc;
    if (RELU) { r0 = fmaxf(r0, 0.f); r1 = fmaxf(r1, 0.f); }
    ((float2*)out)[(size_t)node * TPN + t] = make_float2(r0, r1);
}

// ---------------- launch ----------------

extern "C" void kernel_launch(void* const* d_in, const int* in_sizes, int n_in,
                              void* d_out, int out_size, void* d_ws, size_t ws_size,
                              hipStream_t stream) {
    const float* x   = (const float*)d_in[0];
    const float* Ws0 = (const float*)d_in[1];
    const float* Wn0 = (const float*)d_in[2];
    const float* b0  = (const float*)d_in[3];
    const float* Ws1 = (const float*)d_in[4];
    const float* Wn1 = (const float*)d_in[5];
    const float* b1  = (const float*)d_in[6];
    const float* Ws2 = (const float*)d_in[7];
    const float* Wn2 = (const float*)d_in[8];
    const float* b2  = (const float*)d_in[9];
    const int* esrc  = (const int*)d_in[10];
    const int* edst  = (const int*)d_in[11];
    float* out = (float*)d_out;

    // workspace layout (4B elems; float4 users 16B-aligned)
    float* hA = (float*)d_ws;                         // NN*128 f32
    float* hB = hA + (size_t)NN * 128;                // NN*128 f32
    float* hs = hB + (size_t)NN * 128;                // NN*128 f32
    unsigned* hnu = (unsigned*)(hs + (size_t)NN * 128); // NN*64 u32 (bf16 pairs)
    unsigned* tmp = hnu + (size_t)NN * 64;            // NE u32 packed edges
    int* ssrc = (int*)(tmp + NE);                     // NE
    int* offs = ssrc + NE;                            // NN+1
    int* blockhist = offs + NN + 1;                   // NBLKA*NBINS
    int* offmat = blockhist + NBLKA * NBINS;          // NBINS*NBLKA
    int* binstart = offmat + NBINS * NBLKA;           // NBINS+1
    __hip_bfloat16* hnb = (__hip_bfloat16*)hnu;

    // CSR build: two-level counting sort (no global atomics, coalesced writes)
    hist_k<<<NBLKA, 256, 0, stream>>>(edst, blockhist);
    scan2_k<<<1, 256, 0, stream>>>(blockhist, offmat, binstart);
    scatter_k<<<NBLKA, 256, 0, stream>>>(esrc, edst, offmat, binstart, tmp);

    // fine sort fused with layer-0 dense (independent work, one dispatch)
    sortC_dense0<<<NBINS + 313, 256, 0, stream>>>(tmp, binstart, offs, ssrc,
                                                  x, Ws0, Wn0, b0, hs, hnb);
    agg_combine<128, true><<<(NN + 3) / 4, 256, 0, stream>>>(hs, hnu, offs, ssrc, hA, NN);

    dense_dual<128><<<313, 256, 0, stream>>>(hA, Ws1, Wn1, b1, hs, hnb);
    agg_combine<128, true><<<(NN + 3) / 4, 256, 0, stream>>>(hs, hnu, offs, ssrc, hB, NN);

    dense_dual<64><<<313, 256, 0, stream>>>(hB, Ws2, Wn2, b2, hs, hnb);
    agg_combine<64, false><<<(NN + 7) / 8, 256, 0, stream>>>(hs, hnu, offs, ssrc, out, NN);
}

// Round 3
// 239.859 us; speedup vs baseline: 1.5109x; 1.1707x over previous
//
#include <hip/hip_runtime.h>
#include <hip/hip_bf16.h>

// GraphSAGE 3-layer, N=10000, E=640000, D=128->128->64.
// - Aggregate AFTER the neighbor matmul (linearity of mean aggregation).
// - CSR built via two-level LDS counting sort (no global atomics, no 4B-granule
//   scattered stores).
// - R3: scan stage parallelized (R2's single-block scan2_k was a ~100us serial
//   latency tail: 78K strided L2 reads on one CU). Now 313-block LDS scan +
//   tiny 313-element top scan.
// - Neighbor table bf16 (2.56MB, L2-resident), gathered as uint2 (4 bf16/lane).
// - Layer-0 dense fused into the fine-sort dispatch (independent work).

#define NN 10000
#define NE 640000
#define NBINS 313      // coarse bin = dst >> 5 (32 nodes per bin)
#define NBLKA 250      // histogram/scatter blocks
#define CHUNK 2560     // edges per block (250*2560 == 640000)
#define SORT_CAP 4096  // LDS staging ints for fine sort (expected ~2048/bin)

// ---------------- pass A: per-block coarse histograms (LDS atomics only) ----

__global__ void hist_k(const int* __restrict__ dst, int* __restrict__ blockhist) {
    __shared__ int h[NBINS];
    int tid = threadIdx.x;
    for (int i = tid; i < NBINS; i += 256) h[i] = 0;
    __syncthreads();
    int base = blockIdx.x * CHUNK;
    for (int i = tid; i < CHUNK; i += 256)
        atomicAdd(&h[dst[base + i] >> 5], 1);
    __syncthreads();
    for (int i = tid; i < NBINS; i += 256)
        blockhist[blockIdx.x * NBINS + i] = h[i];
}

// ---------------- pass S: parallel scan of the (block,bin) matrix -----------
// scan2a: one block per bin; exclusive scan over the 250 per-block counts.

__global__ void scan2a_k(const int* __restrict__ blockhist,
                         int* __restrict__ offmat, int* __restrict__ totbin) {
    __shared__ int s[256];
    int bin = blockIdx.x, tid = threadIdx.x;
    int v = (tid < NBLKA) ? blockhist[tid * NBINS + bin] : 0;
    s[tid] = v;
    __syncthreads();
    for (int off = 1; off < 256; off <<= 1) {
        int t = (tid >= off) ? s[tid - off] : 0;
        __syncthreads();
        s[tid] += t;
        __syncthreads();
    }
    if (tid < NBLKA) offmat[bin * NBLKA + tid] = s[tid] - v;   // exclusive
    if (tid == 255) totbin[bin] = s[255];
}

// scan2b: one block; exclusive scan over 313 bin totals -> binstart[0..NBINS].

__global__ void scan2b_k(const int* __restrict__ totbin, int* __restrict__ binstart) {
    __shared__ int s[512];
    int tid = threadIdx.x;
    int v = (tid < NBINS) ? totbin[tid] : 0;
    s[tid] = v;
    __syncthreads();
    for (int off = 1; off < 512; off <<= 1) {
        int t = (tid >= off) ? s[tid - off] : 0;
        __syncthreads();
        s[tid] += t;
        __syncthreads();
    }
    if (tid < NBINS) binstart[tid] = s[tid] - v;               // exclusive
    if (tid == 511) binstart[NBINS] = s[511];                  // == NE
}

// ---------------- pass B: scatter packed edges into bin-grouped tmp ---------

__global__ void scatter_k(const int* __restrict__ src, const int* __restrict__ dst,
                          const int* __restrict__ offmat, const int* __restrict__ binstart,
                          unsigned* __restrict__ tmp) {
    __shared__ int cur[NBINS];
    int tid = threadIdx.x, blk = blockIdx.x;
    for (int i = tid; i < NBINS; i += 256)
        cur[i] = binstart[i] + offmat[i * NBLKA + blk];
    __syncthreads();
    int base = blk * CHUNK;
    for (int i = tid; i < CHUNK; i += 256) {
        int d = dst[base + i], s = src[base + i];
        int pos = atomicAdd(&cur[d >> 5], 1);
        tmp[pos] = ((unsigned)s << 5) | (unsigned)(d & 31);   // src:14b | dstloc:5b
    }
}

// ---------------- pass C: per-bin fine sort -> offs[] + ssrc[] --------------

__device__ void bin_sort_body(const unsigned* __restrict__ tmp,
                              const int* __restrict__ binstart,
                              int* __restrict__ offs, int* __restrict__ ssrc,
                              int b, int* stage) {
    __shared__ int cnt32[32];
    __shared__ int cur32[32];
    int tid = threadIdx.x;
    int beg = binstart[b], end = binstart[b + 1], cnt = end - beg;
    if (tid < 32) cnt32[tid] = 0;
    __syncthreads();
    for (int i = tid; i < cnt; i += 256)
        atomicAdd(&cnt32[tmp[beg + i] & 31], 1);
    __syncthreads();
    if (tid == 0) {
        int run = 0;
        for (int i = 0; i < 32; ++i) {
            int node = b * 32 + i;
            if (node < NN) offs[node] = beg + run;
            cur32[i] = run;
            run += cnt32[i];
        }
        if (b == NBINS - 1) offs[NN] = end;
    }
    __syncthreads();
    if (cnt <= SORT_CAP) {
        for (int i = tid; i < cnt; i += 256) {
            unsigned p = tmp[beg + i];
            int pos = atomicAdd(&cur32[p & 31], 1);
            stage[pos] = (int)(p >> 5);
        }
        __syncthreads();
        for (int i = tid; i < cnt; i += 256)   // coalesced stream-out
            ssrc[beg + i] = stage[i];
    } else {                                    // safety fallback (never expected)
        for (int i = tid; i < cnt; i += 256) {
            unsigned p = tmp[beg + i];
            int pos = atomicAdd(&cur32[p & 31], 1);
            ssrc[beg + pos] = (int)(p >> 5);
        }
    }
}

// ---------------- dense dual matmul: hs = h@Ws + b (f32), hnb = h@Wn (bf16) -

template <int M>
__device__ void dense_body(const float* __restrict__ h,
                           const float* __restrict__ Ws,
                           const float* __restrict__ Wn,
                           const float* __restrict__ bias,
                           float* __restrict__ hs, __hip_bfloat16* __restrict__ hnb,
                           int blk, float* sh) {
    constexpr int K = 128;
    constexpr int ROWS = 32;
    constexpr int R = ROWS * M / 256;      // rows per thread
    int row0 = blk * ROWS;
    int tid = threadIdx.x;

    constexpr int NVEC = ROWS * K / 4;     // 1024 float4s
    const float4* hv = (const float4*)(h + (size_t)row0 * K);
    float4* shv = (float4*)sh;
    int maxvec = (NN - row0) * (K / 4);
    for (int i = tid; i < NVEC; i += 256)
        shv[i] = (i < maxvec) ? hv[i] : make_float4(0.f, 0.f, 0.f, 0.f);
    __syncthreads();

    int col = tid % M;
    int rg = tid / M;
    float accs[R], accn[R];
#pragma unroll
    for (int r = 0; r < R; ++r) { accs[r] = 0.f; accn[r] = 0.f; }

    for (int k = 0; k < K; k += 4) {
        float ws0 = Ws[(k + 0) * M + col];
        float ws1 = Ws[(k + 1) * M + col];
        float ws2 = Ws[(k + 2) * M + col];
        float ws3 = Ws[(k + 3) * M + col];
        float wn0 = Wn[(k + 0) * M + col];
        float wn1 = Wn[(k + 1) * M + col];
        float wn2 = Wn[(k + 2) * M + col];
        float wn3 = Wn[(k + 3) * M + col];
#pragma unroll
        for (int r = 0; r < R; ++r) {
            float4 a = *(const float4*)&sh[(rg * R + r) * K + k];
            accs[r] += a.x * ws0 + a.y * ws1 + a.z * ws2 + a.w * ws3;
            accn[r] += a.x * wn0 + a.y * wn1 + a.z * wn2 + a.w * wn3;
        }
    }

    float bv = bias[col];
#pragma unroll
    for (int r = 0; r < R; ++r) {
        int row = row0 + rg * R + r;
        if (row < NN) {
            hs[(size_t)row * M + col] = accs[r] + bv;
            hnb[(size_t)row * M + col] = __float2bfloat16(accn[r]);
        }
    }
}

template <int M>
__global__ void dense_dual(const float* __restrict__ h, const float* __restrict__ Ws,
                           const float* __restrict__ Wn, const float* __restrict__ b,
                           float* __restrict__ hs, __hip_bfloat16* __restrict__ hnb) {
    __shared__ float4 sh4[32 * 128 / 4];
    dense_body<M>(h, Ws, Wn, b, hs, hnb, blockIdx.x, (float*)sh4);
}

// fused: blocks [0,NBINS) fine-sort, blocks [NBINS, NBINS+313) dense layer 0
__global__ void sortC_dense0(const unsigned* __restrict__ tmp, const int* __restrict__ binstart,
                             int* __restrict__ offs, int* __restrict__ ssrc,
                             const float* __restrict__ x, const float* __restrict__ Ws0,
                             const float* __restrict__ Wn0, const float* __restrict__ b0,
                             float* __restrict__ hs, __hip_bfloat16* __restrict__ hnb) {
    __shared__ float4 shb[SORT_CAP / 4];   // 16KB, shared by both roles
    if ((int)blockIdx.x < NBINS)
        bin_sort_body(tmp, binstart, offs, ssrc, blockIdx.x, (int*)shb);
    else
        dense_body<128>(x, Ws0, Wn0, b0, hs, hnb, blockIdx.x - NBINS, (float*)shb);
}

// ---------------- fused aggregate + combine (+ReLU), bf16 uint2 gathers -----
// out[node] = hs[node] + (sum over CSR(node) of hnb[src]) / max(deg,1)

__device__ __forceinline__ float bf_lo(unsigned u) { return __uint_as_float(u << 16); }
__device__ __forceinline__ float bf_hi(unsigned u) { return __uint_as_float(u & 0xFFFF0000u); }

template <int M, bool RELU>
__global__ void agg_combine(const float* __restrict__ hs, const uint2* __restrict__ hn2,
                            const int* __restrict__ offs, const int* __restrict__ ssrc,
                            float* __restrict__ out, int n) {
    constexpr int TPN = M / 4;             // threads per node (4 bf16 feats each)
    constexpr int NPB = 256 / TPN;         // nodes per block
    int node = blockIdx.x * NPB + threadIdx.x / TPN;
    int t = threadIdx.x % TPN;
    if (node >= n) return;
    int beg = offs[node], end = offs[node + 1];
    float a0 = 0.f, a1 = 0.f, a2 = 0.f, a3 = 0.f;
    int e = beg;
    for (; e + 4 <= end; e += 4) {
        int s0 = ssrc[e], s1 = ssrc[e + 1], s2 = ssrc[e + 2], s3 = ssrc[e + 3];
        uint2 v0 = hn2[(size_t)s0 * TPN + t];
        uint2 v1 = hn2[(size_t)s1 * TPN + t];
        uint2 v2 = hn2[(size_t)s2 * TPN + t];
        uint2 v3 = hn2[(size_t)s3 * TPN + t];
        a0 += bf_lo(v0.x) + bf_lo(v1.x) + bf_lo(v2.x) + bf_lo(v3.x);
        a1 += bf_hi(v0.x) + bf_hi(v1.x) + bf_hi(v2.x) + bf_hi(v3.x);
        a2 += bf_lo(v0.y) + bf_lo(v1.y) + bf_lo(v2.y) + bf_lo(v3.y);
        a3 += bf_hi(v0.y) + bf_hi(v1.y) + bf_hi(v2.y) + bf_hi(v3.y);
    }
    for (; e < end; ++e) {
        uint2 v = hn2[(size_t)ssrc[e] * TPN + t];
        a0 += bf_lo(v.x); a1 += bf_hi(v.x); a2 += bf_lo(v.y); a3 += bf_hi(v.y);
    }
    int deg = end - beg;
    float sc = 1.0f / (float)(deg > 0 ? deg : 1);
    float4 h4 = ((const float4*)hs)[(size_t)node * TPN + t];
    float r0 = h4.x + a0 * sc;
    float r1 = h4.y + a1 * sc;
    float r2 = h4.z + a2 * sc;
    float r3 = h4.w + a3 * sc;
    if (RELU) {
        r0 = fmaxf(r0, 0.f); r1 = fmaxf(r1, 0.f);
        r2 = fmaxf(r2, 0.f); r3 = fmaxf(r3, 0.f);
    }
    ((float4*)out)[(size_t)node * TPN + t] = make_float4(r0, r1, r2, r3);
}

// ---------------- launch ----------------

extern "C" void kernel_launch(void* const* d_in, const int* in_sizes, int n_in,
                              void* d_out, int out_size, void* d_ws, size_t ws_size,
                              hipStream_t stream) {
    const float* x   = (const float*)d_in[0];
    const float* Ws0 = (const float*)d_in[1];
    const float* Wn0 = (const float*)d_in[2];
    const float* b0  = (const float*)d_in[3];
    const float* Ws1 = (const float*)d_in[4];
    const float* Wn1 = (const float*)d_in[5];
    const float* b1  = (const float*)d_in[6];
    const float* Ws2 = (const float*)d_in[7];
    const float* Wn2 = (const float*)d_in[8];
    const float* b2  = (const float*)d_in[9];
    const int* esrc  = (const int*)d_in[10];
    const int* edst  = (const int*)d_in[11];
    float* out = (float*)d_out;

    // workspace layout (4B elems; float4 users 16B-aligned)
    float* hA = (float*)d_ws;                           // NN*128 f32
    float* hB = hA + (size_t)NN * 128;                  // NN*128 f32
    float* hs = hB + (size_t)NN * 128;                  // NN*128 f32
    unsigned* hnu = (unsigned*)(hs + (size_t)NN * 128); // NN*64 u32 (bf16 pairs)
    unsigned* tmp = hnu + (size_t)NN * 64;              // NE u32 packed edges
    int* ssrc = (int*)(tmp + NE);                       // NE
    int* offs = ssrc + NE;                              // NN+1
    int* blockhist = offs + NN + 1;                     // NBLKA*NBINS
    int* offmat = blockhist + NBLKA * NBINS;            // NBINS*NBLKA
    int* binstart = offmat + NBINS * NBLKA;             // NBINS+1
    int* totbin = binstart + NBINS + 1;                 // NBINS
    __hip_bfloat16* hnb = (__hip_bfloat16*)hnu;
    const uint2* hn2 = (const uint2*)hnu;

    // CSR build: two-level counting sort (no global atomics, coalesced writes)
    hist_k<<<NBLKA, 256, 0, stream>>>(edst, blockhist);
    scan2a_k<<<NBINS, 256, 0, stream>>>(blockhist, offmat, totbin);
    scan2b_k<<<1, 512, 0, stream>>>(totbin, binstart);
    scatter_k<<<NBLKA, 256, 0, stream>>>(esrc, edst, offmat, binstart, tmp);

    // fine sort fused with layer-0 dense (independent work, one dispatch)
    sortC_dense0<<<NBINS + 313, 256, 0, stream>>>(tmp, binstart, offs, ssrc,
                                                  x, Ws0, Wn0, b0, hs, hnb);
    agg_combine<128, true><<<(NN + 7) / 8, 256, 0, stream>>>(hs, hn2, offs, ssrc, hA, NN);

    dense_dual<128><<<313, 256, 0, stream>>>(hA, Ws1, Wn1, b1, hs, hnb);
    agg_combine<128, true><<<(NN + 7) / 8, 256, 0, stream>>>(hs, hn2, offs, ssrc, hB, NN);

    dense_dual<64><<<313, 256, 0, stream>>>(hB, Ws2, Wn2, b2, hs, hnb);
    agg_combine<64, false><<<(NN + 15) / 16, 256, 0, stream>>>(hs, hn2, offs, ssrc, out, NN);
}

// Round 4
// 196.346 us; speedup vs baseline: 1.8458x; 1.2216x over previous
//
#include <hip/hip_runtime.h>

// GraphSAGE 3-layer, N=10000, E=640000, D=128->128->64, MI355X.
// R4: 6 dispatches (was 10).
//  P0 hist + bf16 prep (x->bf16, W->W^T bf16)         [320 blocks]
//  P1 scatter w/ inline redundant scan of blockhist    [250]
//  P2 per-bin fine sort + MFMA dense0 (x@Ws0/Wn0)      [313+313]
//  P3 agg layer0 + relu + MFMA dense1 (fused via LDS)  [625]
//  P4 agg layer1 + relu + MFMA dense2 (fused via LDS)  [625]
//  P5 agg layer2 -> d_out                              [313]
// Aggregation is post-matmul (linearity of mean agg). Neighbor tables and
// dense inputs are bf16 (fp32 accumulate everywhere); self path hs stays fp32.
// MFMA layouts (verified, guide §3): A[m=lane&15][k=quad*8+j],
// B[n=lane&15][k=quad*8+j] (i.e. A·B^T with W^T staged), C/D col=lane&15,
// row=quad*4+reg.

#define NN 10000
#define NE 640000
#define NBINS 313      // coarse bin = dst >> 5
#define NBLKA 250
#define CHUNK 2560     // 250*2560 == NE
#define SORT_CAP 4096

typedef __attribute__((ext_vector_type(8))) short s8v;   // 8 bf16 (4 VGPRs)
typedef __attribute__((ext_vector_type(4))) float f4v;   // MFMA C/D

__device__ __forceinline__ ushort f2bf(float f) {        // RNE f32->bf16
    unsigned u = __float_as_uint(f);
    return (ushort)((u + 0x7FFFu + ((u >> 16) & 1u)) >> 16);
}
__device__ __forceinline__ unsigned pack2(float a, float b) {
    return (unsigned)f2bf(a) | ((unsigned)f2bf(b) << 16);
}
__device__ __forceinline__ float bf_lo(unsigned u) { return __uint_as_float(u << 16); }
__device__ __forceinline__ float bf_hi(unsigned u) { return __uint_as_float(u & 0xFFFF0000u); }

// ---------------- P0: histogram + bf16 prep ----------------

__global__ void hist_prep_k(const int* __restrict__ edst, int* __restrict__ blockhist,
                            const float* __restrict__ x, ushort* __restrict__ xb,
                            const float* __restrict__ Ws0, const float* __restrict__ Wn0,
                            const float* __restrict__ Ws1, const float* __restrict__ Wn1,
                            const float* __restrict__ Ws2, const float* __restrict__ Wn2,
                            ushort* __restrict__ wt) {
    __shared__ int h[NBINS];
    int blk = blockIdx.x, tid = threadIdx.x;
    if (blk < NBLKA) {                       // histogram role
        for (int i = tid; i < NBINS; i += 256) h[i] = 0;
        __syncthreads();
        int base = blk * CHUNK;
        for (int i = tid; i < CHUNK; i += 256)
            atomicAdd(&h[edst[base + i] >> 5], 1);
        __syncthreads();
        for (int i = tid; i < NBINS; i += 256)
            blockhist[blk * NBINS + i] = h[i];
    } else if (blk < NBLKA + 64) {           // x -> bf16 (320000 float4 total)
        int cb = blk - NBLKA;
        const float4* xv = (const float4*)x;
        uint2* xo = (uint2*)xb;
        for (int i = tid; i < 5000; i += 256) {
            int idx = cb * 5000 + i;
            float4 v = xv[idx];
            xo[idx] = make_uint2(pack2(v.x, v.y), pack2(v.z, v.w));
        }
    } else {                                 // 6 weight transposes -> W^T bf16
        int m = blk - NBLKA - 64;            // 0..5
        const float* W = (m == 0) ? Ws0 : (m == 1) ? Wn0 : (m == 2) ? Ws1
                       : (m == 3) ? Wn1 : (m == 4) ? Ws2 : Wn2;
        int MC = (m < 4) ? 128 : 64;
        ushort* dst = wt + ((m < 4) ? m * 16384 : 65536 + (m - 4) * 8192);
        int tot = 128 * MC;
        for (int idx = tid; idx < tot; idx += 256) {
            int k = (MC == 128) ? (idx >> 7) : (idx >> 6);
            int n = (MC == 128) ? (idx & 127) : (idx & 63);
            dst[n * 128 + k] = f2bf(W[idx]);
        }
    }
}

// ---------------- P1: scatter with inline scan ----------------

__global__ void scatter_k(const int* __restrict__ src, const int* __restrict__ dst,
                          const int* __restrict__ blockhist,
                          int* __restrict__ binstart_g, unsigned* __restrict__ tmp) {
    __shared__ int sa[512], sb[512];
    __shared__ int cur[NBINS];
    int blk = blockIdx.x, tid = threadIdx.x;
    int bin0 = tid, bin1 = tid + 256;
    int stot0 = 0, smine0 = 0, stot1 = 0, smine1 = 0;
    for (int b = 0; b < NBLKA; ++b) {        // coalesced: consecutive bins/lane
        int v0 = blockhist[b * NBINS + bin0];
        int v1 = (bin1 < NBINS) ? blockhist[b * NBINS + bin1] : 0;
        stot0 += v0; stot1 += v1;
        if (b < blk) { smine0 += v0; smine1 += v1; }
    }
    sa[bin0] = stot0; sa[bin1] = stot1;
    __syncthreads();
    int* pa = sa; int* pb = sb;
    for (int off = 1; off < 512; off <<= 1) {   // Hillis-Steele, ping-pong
        int x0 = pa[bin0] + ((bin0 >= off) ? pa[bin0 - off] : 0);
        int x1 = pa[bin1] + ((bin1 >= off) ? pa[bin1 - off] : 0);
        pb[bin0] = x0; pb[bin1] = x1;
        __syncthreads();
        int* t = pa; pa = pb; pb = t;
    }
    int bs0 = pa[bin0] - stot0;              // exclusive binstart
    cur[bin0] = bs0 + smine0;
    int bs1 = 0;
    if (bin1 < NBINS) { bs1 = pa[bin1] - stot1; cur[bin1] = bs1 + smine1; }
    if (blk == 0) {
        binstart_g[bin0] = bs0;
        if (bin1 < NBINS) binstart_g[bin1] = bs1;
        if (tid == 0) binstart_g[NBINS] = pa[NBINS - 1];
    }
    __syncthreads();
    int base = blk * CHUNK;
    for (int i = tid; i < CHUNK; i += 256) {
        int d = dst[base + i], s = src[base + i];
        int pos = atomicAdd(&cur[d >> 5], 1);
        tmp[pos] = ((unsigned)s << 5) | (unsigned)(d & 31);
    }
}

// ---------------- P2: fine sort + MFMA dense0 ----------------

__device__ void bin_sort_body(const unsigned* __restrict__ tmp,
                              const int* __restrict__ binstart,
                              int* __restrict__ offs, int* __restrict__ ssrc,
                              int b, int* stage) {
    __shared__ int cnt32[32];
    __shared__ int cur32[32];
    int tid = threadIdx.x;
    int beg = binstart[b], end = binstart[b + 1], cnt = end - beg;
    if (tid < 32) cnt32[tid] = 0;
    __syncthreads();
    for (int i = tid; i < cnt; i += 256)
        atomicAdd(&cnt32[tmp[beg + i] & 31], 1);
    __syncthreads();
    if (tid == 0) {
        int run = 0;
        for (int i = 0; i < 32; ++i) {
            int node = b * 32 + i;
            if (node < NN) offs[node] = beg + run;
            cur32[i] = run;
            run += cnt32[i];
        }
        if (b == NBINS - 1) offs[NN] = end;
    }
    __syncthreads();
    if (cnt <= SORT_CAP) {
        for (int i = tid; i < cnt; i += 256) {
            unsigned p = tmp[beg + i];
            int pos = atomicAdd(&cur32[p & 31], 1);
            stage[pos] = (int)(p >> 5);
        }
        __syncthreads();
        for (int i = tid; i < cnt; i += 256)
            ssrc[beg + i] = stage[i];
    } else {
        for (int i = tid; i < cnt; i += 256) {
            unsigned p = tmp[beg + i];
            int pos = atomicAdd(&cur32[p & 31], 1);
            ssrc[beg + pos] = (int)(p >> 5);
        }
    }
}

__global__ void sort_dense0_k(const unsigned* __restrict__ tmp, const int* __restrict__ binstart,
                              int* __restrict__ offs, int* __restrict__ ssrc,
                              const ushort* __restrict__ xb, const ushort* __restrict__ wt,
                              const float* __restrict__ b0,
                              float* __restrict__ hs, ushort* __restrict__ hn) {
    __shared__ int stage[SORT_CAP];
    int blk = blockIdx.x;
    if (blk < NBINS) { bin_sort_body(tmp, binstart, offs, ssrc, blk, stage); return; }

    // MFMA dense0: 32 rows/block, A straight from global bf16
    int dblk = blk - NBINS;
    int l = threadIdx.x & 63, w = threadIdx.x >> 6;
    int mloc = l & 15, quad = l >> 4;
    int row_base = dblk * 32 + (w & 1) * 16;
    int colh = w >> 1;
    int arow = row_base + mloc;
    int arow_c = (arow < NN) ? arow : (NN - 1);
    const ushort* wsT = wt;                  // Ws0^T
    const ushort* wnT = wt + 16384;          // Wn0^T
    f4v accS[4], accN[4];
#pragma unroll
    for (int nt = 0; nt < 4; ++nt) { accS[nt] = (f4v){0,0,0,0}; accN[nt] = (f4v){0,0,0,0}; }
#pragma unroll
    for (int ks = 0; ks < 4; ++ks) {
        int kb = ks * 32 + quad * 8;
        s8v a = *(const s8v*)(xb + (size_t)arow_c * 128 + kb);
#pragma unroll
        for (int nt = 0; nt < 4; ++nt) {
            int n = colh * 64 + nt * 16 + mloc;
            s8v bs = *(const s8v*)(wsT + n * 128 + kb);
            s8v bn = *(const s8v*)(wnT + n * 128 + kb);
            accS[nt] = __builtin_amdgcn_mfma_f32_16x16x32_bf16(a, bs, accS[nt], 0, 0, 0);
            accN[nt] = __builtin_amdgcn_mfma_f32_16x16x32_bf16(a, bn, accN[nt], 0, 0, 0);
        }
    }
#pragma unroll
    for (int nt = 0; nt < 4; ++nt) {
        int col = colh * 64 + nt * 16 + mloc;
        float bv = b0[col];
#pragma unroll
        for (int r = 0; r < 4; ++r) {
            int row = row_base + quad * 4 + r;
            if (row < NN) {
                hs[(size_t)row * 128 + col] = accS[nt][r] + bv;
                hn[(size_t)row * 128 + col] = f2bf(accN[nt][r]);
            }
        }
    }
}

// ---------------- P3/P4: agg + relu + fused MFMA dense ----------------
// Block = 16 nodes (625*16 == NN exactly). Gather -> LDS rows -> MFMA.

template <int MOUT>
__global__ void agg_dense_k(const float* __restrict__ hs_in, const ushort* __restrict__ hn_in,
                            const int* __restrict__ offs, const int* __restrict__ ssrc,
                            const ushort* __restrict__ wsT, const ushort* __restrict__ wnT,
                            const float* __restrict__ bias,
                            float* __restrict__ hs_out, ushort* __restrict__ hn_out) {
    __shared__ ushort hrow[16 * 136];        // pad 128->136 vs LDS banks
    int tid = threadIdx.x;
    int node_loc = tid >> 4, t = tid & 15;
    int node = blockIdx.x * 16 + node_loc;
    int beg = offs[node], end = offs[node + 1];
    const uint4* hn4 = (const uint4*)hn_in;
    float a0 = 0, a1 = 0, a2 = 0, a3 = 0, a4 = 0, a5 = 0, a6 = 0, a7 = 0;
    int e = beg;
    for (; e + 4 <= end; e += 4) {
        int s0 = ssrc[e], s1 = ssrc[e + 1], s2 = ssrc[e + 2], s3 = ssrc[e + 3];
        uint4 v0 = hn4[(size_t)s0 * 16 + t];
        uint4 v1 = hn4[(size_t)s1 * 16 + t];
        uint4 v2 = hn4[(size_t)s2 * 16 + t];
        uint4 v3 = hn4[(size_t)s3 * 16 + t];
        a0 += bf_lo(v0.x) + bf_lo(v1.x) + bf_lo(v2.x) + bf_lo(v3.x);
        a1 += bf_hi(v0.x) + bf_hi(v1.x) + bf_hi(v2.x) + bf_hi(v3.x);
        a2 += bf_lo(v0.y) + bf_lo(v1.y) + bf_lo(v2.y) + bf_lo(v3.y);
        a3 += bf_hi(v0.y) + bf_hi(v1.y) + bf_hi(v2.y) + bf_hi(v3.y);
        a4 += bf_lo(v0.z) + bf_lo(v1.z) + bf_lo(v2.z) + bf_lo(v3.z);
        a5 += bf_hi(v0.z) + bf_hi(v1.z) + bf_hi(v2.z) + bf_hi(v3.z);
        a6 += bf_lo(v0.w) + bf_lo(v1.w) + bf_lo(v2.w) + bf_lo(v3.w);
        a7 += bf_hi(v0.w) + bf_hi(v1.w) + bf_hi(v2.w) + bf_hi(v3.w);
    }
    for (; e < end; ++e) {
        uint4 v = hn4[(size_t)ssrc[e] * 16 + t];
        a0 += bf_lo(v.x); a1 += bf_hi(v.x); a2 += bf_lo(v.y); a3 += bf_hi(v.y);
        a4 += bf_lo(v.z); a5 += bf_hi(v.z); a6 += bf_lo(v.w); a7 += bf_hi(v.w);
    }
    int deg = end - beg;
    float sc = 1.0f / (float)(deg > 0 ? deg : 1);
    float4 h4a = ((const float4*)hs_in)[(size_t)node * 32 + 2 * t];
    float4 h4b = ((const float4*)hs_in)[(size_t)node * 32 + 2 * t + 1];
    float r0 = fmaxf(h4a.x + a0 * sc, 0.f), r1 = fmaxf(h4a.y + a1 * sc, 0.f);
    float r2 = fmaxf(h4a.z + a2 * sc, 0.f), r3 = fmaxf(h4a.w + a3 * sc, 0.f);
    float r4 = fmaxf(h4b.x + a4 * sc, 0.f), r5 = fmaxf(h4b.y + a5 * sc, 0.f);
    float r6 = fmaxf(h4b.z + a6 * sc, 0.f), r7 = fmaxf(h4b.w + a7 * sc, 0.f);
    *(uint4*)(hrow + node_loc * 136 + t * 8) =
        make_uint4(pack2(r0, r1), pack2(r2, r3), pack2(r4, r5), pack2(r6, r7));
    __syncthreads();

    // dense: D[16 x MOUT] = H[16x128] @ {Ws|Wn}, fp32 acc
    int l = tid & 63, w = tid >> 6;
    int mloc = l & 15, quad = l >> 4;
    constexpr int NTPW = MOUT / 64;          // n-tiles per wave
    f4v accS[NTPW], accN[NTPW];
#pragma unroll
    for (int nt = 0; nt < NTPW; ++nt) { accS[nt] = (f4v){0,0,0,0}; accN[nt] = (f4v){0,0,0,0}; }
#pragma unroll
    for (int ks = 0; ks < 4; ++ks) {
        int kb = ks * 32 + quad * 8;
        s8v a = *(const s8v*)(hrow + mloc * 136 + kb);
#pragma unroll
        for (int nt = 0; nt < NTPW; ++nt) {
            int n = (w * NTPW + nt) * 16 + mloc;
            s8v bs = *(const s8v*)(wsT + n * 128 + kb);
            s8v bn = *(const s8v*)(wnT + n * 128 + kb);
            accS[nt] = __builtin_amdgcn_mfma_f32_16x16x32_bf16(a, bs, accS[nt], 0, 0, 0);
            accN[nt] = __builtin_amdgcn_mfma_f32_16x16x32_bf16(a, bn, accN[nt], 0, 0, 0);
        }
    }
#pragma unroll
    for (int nt = 0; nt < NTPW; ++nt) {
        int col = (w * NTPW + nt) * 16 + mloc;
        float bv = bias[col];
#pragma unroll
        for (int r = 0; r < 4; ++r) {
            int row = blockIdx.x * 16 + quad * 4 + r;   // always < NN
            hs_out[(size_t)row * MOUT + col] = accS[nt][r] + bv;
            hn_out[(size_t)row * MOUT + col] = f2bf(accN[nt][r]);
        }
    }
}

// ---------------- P5: final aggregate (M=64) -> d_out ----------------

__global__ void agg_out_k(const float* __restrict__ hs_in, const ushort* __restrict__ hn_in,
                          const int* __restrict__ offs, const int* __restrict__ ssrc,
                          float* __restrict__ out) {
    int tid = threadIdx.x;
    int node = blockIdx.x * 32 + (tid >> 3);
    int t = tid & 7;
    if (node >= NN) return;
    int beg = offs[node], end = offs[node + 1];
    const uint4* hn4 = (const uint4*)hn_in;
    float a0 = 0, a1 = 0, a2 = 0, a3 = 0, a4 = 0, a5 = 0, a6 = 0, a7 = 0;
    int e = beg;
    for (; e + 4 <= end; e += 4) {
        int s0 = ssrc[e], s1 = ssrc[e + 1], s2 = ssrc[e + 2], s3 = ssrc[e + 3];
        uint4 v0 = hn4[(size_t)s0 * 8 + t];
        uint4 v1 = hn4[(size_t)s1 * 8 + t];
        uint4 v2 = hn4[(size_t)s2 * 8 + t];
        uint4 v3 = hn4[(size_t)s3 * 8 + t];
        a0 += bf_lo(v0.x) + bf_lo(v1.x) + bf_lo(v2.x) + bf_lo(v3.x);
        a1 += bf_hi(v0.x) + bf_hi(v1.x) + bf_hi(v2.x) + bf_hi(v3.x);
        a2 += bf_lo(v0.y) + bf_lo(v1.y) + bf_lo(v2.y) + bf_lo(v3.y);
        a3 += bf_hi(v0.y) + bf_hi(v1.y) + bf_hi(v2.y) + bf_hi(v3.y);
        a4 += bf_lo(v0.z) + bf_lo(v1.z) + bf_lo(v2.z) + bf_lo(v3.z);
        a5 += bf_hi(v0.z) + bf_hi(v1.z) + bf_hi(v2.z) + bf_hi(v3.z);
        a6 += bf_lo(v0.w) + bf_lo(v1.w) + bf_lo(v2.w) + bf_lo(v3.w);
        a7 += bf_hi(v0.w) + bf_hi(v1.w) + bf_hi(v2.w) + bf_hi(v3.w);
    }
    for (; e < end; ++e) {
        uint4 v = hn4[(size_t)ssrc[e] * 8 + t];
        a0 += bf_lo(v.x); a1 += bf_hi(v.x); a2 += bf_lo(v.y); a3 += bf_hi(v.y);
        a4 += bf_lo(v.z); a5 += bf_hi(v.z); a6 += bf_lo(v.w); a7 += bf_hi(v.w);
    }
    int deg = end - beg;
    float sc = 1.0f / (float)(deg > 0 ? deg : 1);
    float4 h4a = ((const float4*)hs_in)[(size_t)node * 16 + 2 * t];
    float4 h4b = ((const float4*)hs_in)[(size_t)node * 16 + 2 * t + 1];
    ((float4*)out)[(size_t)node * 16 + 2 * t] =
        make_float4(h4a.x + a0 * sc, h4a.y + a1 * sc, h4a.z + a2 * sc, h4a.w + a3 * sc);
    ((float4*)out)[(size_t)node * 16 + 2 * t + 1] =
        make_float4(h4b.x + a4 * sc, h4b.y + a5 * sc, h4b.z + a6 * sc, h4b.w + a7 * sc);
}

// ---------------- launch ----------------

extern "C" void kernel_launch(void* const* d_in, const int* in_sizes, int n_in,
                              void* d_out, int out_size, void* d_ws, size_t ws_size,
                              hipStream_t stream) {
    const float* x   = (const float*)d_in[0];
    const float* Ws0 = (const float*)d_in[1];
    const float* Wn0 = (const float*)d_in[2];
    const float* b0  = (const float*)d_in[3];
    const float* Ws1 = (const float*)d_in[4];
    const float* Wn1 = (const float*)d_in[5];
    const float* b1  = (const float*)d_in[6];
    const float* Ws2 = (const float*)d_in[7];
    const float* Wn2 = (const float*)d_in[8];
    const float* b2  = (const float*)d_in[9];
    const int* esrc  = (const int*)d_in[10];
    const int* edst  = (const int*)d_in[11];
    float* out = (float*)d_out;

    // workspace layout (16B-aligned users first)
    float*  hsA = (float*)d_ws;                        // NN*128 f32
    float*  hsB = hsA + (size_t)NN * 128;              // NN*128 f32
    ushort* hnA = (ushort*)(hsB + (size_t)NN * 128);   // NN*128 bf16
    ushort* hnB = hnA + (size_t)NN * 128;              // NN*128 bf16
    ushort* xb  = hnB + (size_t)NN * 128;              // NN*128 bf16
    ushort* wt  = xb + (size_t)NN * 128;               // 81920 bf16 (W^T x6)
    unsigned* tmp = (unsigned*)(wt + 81920);           // NE packed edges
    int* ssrc = (int*)(tmp + NE);                      // NE
    int* offs = ssrc + NE;                             // NN+1
    int* blockhist = offs + NN + 1;                    // NBLKA*NBINS
    int* binstart = blockhist + NBLKA * NBINS;         // NBINS+1

    const ushort* wt0s = wt;
    const ushort* wt0n = wt + 16384;
    const ushort* wt1s = wt + 32768;
    const ushort* wt1n = wt + 49152;
    const ushort* wt2s = wt + 65536;
    const ushort* wt2n = wt + 73728;

    hist_prep_k<<<NBLKA + 64 + 6, 256, 0, stream>>>(edst, blockhist, x, xb,
                                                    Ws0, Wn0, Ws1, Wn1, Ws2, Wn2, wt);
    scatter_k<<<NBLKA, 256, 0, stream>>>(esrc, edst, blockhist, binstart, tmp);
    sort_dense0_k<<<NBINS + 313, 256, 0, stream>>>(tmp, binstart, offs, ssrc,
                                                   xb, wt, b0, hsA, hnA);
    agg_dense_k<128><<<NN / 16, 256, 0, stream>>>(hsA, hnA, offs, ssrc,
                                                  wt1s, wt1n, b1, hsB, hnB);
    agg_dense_k<64><<<NN / 16, 256, 0, stream>>>(hsB, hnB, offs, ssrc,
                                                 wt2s, wt2n, b2, hsA, hnA);
    agg_out_k<<<(NN + 31) / 32, 256, 0, stream>>>(hsA, hnA, offs, ssrc, out);
}